// Round 5
// baseline (3975.381 us; speedup 1.0000x reference)
//
#include <hip/hip_runtime.h>
#include <math.h>

// B=256, T=2048, H=150. Sequential GRU, relu'd hidden, scalar linear head.
// 1 block per batch element (256 blocks = 256 CUs), 512 threads.
//
// Math is EXACTLY the R4 kernel that passed at absmax 4.9e-4. Two additions
// to force the 150 weight scalars to be VGPR-RESIDENT (R1/R2/R4 all showed
// VGPR_Count~90: the scheduler SINKS the loop-invariant const loads back
// into the loop chasing occupancy that the 256-block grid can never use):
//   1. amdgpu_waves_per_eu(2,2): pressure target = 2 waves/EU = 256 VGPRs.
//   2. asm volatile "+v" pin on every weight: an asm redefinition is not
//      rematerializable/sinkable, so the RA must keep them live in VGPRs.

#define BB 256
#define TT 2048
#define HH 150
#define H3 450

__device__ __forceinline__ float rl(float v, int l) {
    return __uint_as_float(__builtin_amdgcn_readlane(__float_as_uint(v), l));
}

__global__ __launch_bounds__(512)
__attribute__((amdgpu_waves_per_eu(2, 2)))
void gru_seq_kernel(
    const float* __restrict__ input,   // [B,T]
    const float* __restrict__ W_ih,    // [450,1]
    const float* __restrict__ W_hh,    // [450,150]
    const float* __restrict__ b_ih,    // [450]
    const float* __restrict__ b_hh,    // [450]
    const float* __restrict__ W_lin,   // [1,150]
    const float* __restrict__ b_lin,   // [1]
    float* __restrict__ out)           // [B,T]
{
    const int b    = blockIdx.x;
    const int tid  = threadIdx.x;
    const int lane = tid & 63;

    __shared__ float  xrow[TT];       // 8 KB: whole input row
    __shared__ float4 h4[64];         // h[0..149] zero-padded to 256 floats
    __shared__ float  pre[H3 + 2];
    __shared__ float  ypart[4];

    // ---- prologue -------------------------------------------------------
    ((float4*)xrow)[tid] = ((const float4*)(input + (size_t)b * TT))[tid];
    if (tid < 64) h4[tid] = make_float4(0.f, 0.f, 0.f, 0.f);
    if (tid < 4)  ypart[tid] = 0.f;

    // Weight row -> 150 named scalars, then asm-pinned into VGPRs.
    const int row = (tid < H3) ? tid : (H3 - 1);
    const float* wr = W_hh + row * HH;
#define LW(i) float w##i = wr[i];
    LW(0)   LW(1)   LW(2)   LW(3)   LW(4)   LW(5)   LW(6)   LW(7)
    LW(8)   LW(9)   LW(10)  LW(11)  LW(12)  LW(13)  LW(14)  LW(15)
    LW(16)  LW(17)  LW(18)  LW(19)  LW(20)  LW(21)  LW(22)  LW(23)
    LW(24)  LW(25)  LW(26)  LW(27)  LW(28)  LW(29)  LW(30)  LW(31)
    LW(32)  LW(33)  LW(34)  LW(35)  LW(36)  LW(37)  LW(38)  LW(39)
    LW(40)  LW(41)  LW(42)  LW(43)  LW(44)  LW(45)  LW(46)  LW(47)
    LW(48)  LW(49)  LW(50)  LW(51)  LW(52)  LW(53)  LW(54)  LW(55)
    LW(56)  LW(57)  LW(58)  LW(59)  LW(60)  LW(61)  LW(62)  LW(63)
    LW(64)  LW(65)  LW(66)  LW(67)  LW(68)  LW(69)  LW(70)  LW(71)
    LW(72)  LW(73)  LW(74)  LW(75)  LW(76)  LW(77)  LW(78)  LW(79)
    LW(80)  LW(81)  LW(82)  LW(83)  LW(84)  LW(85)  LW(86)  LW(87)
    LW(88)  LW(89)  LW(90)  LW(91)  LW(92)  LW(93)  LW(94)  LW(95)
    LW(96)  LW(97)  LW(98)  LW(99)  LW(100) LW(101) LW(102) LW(103)
    LW(104) LW(105) LW(106) LW(107) LW(108) LW(109) LW(110) LW(111)
    LW(112) LW(113) LW(114) LW(115) LW(116) LW(117) LW(118) LW(119)
    LW(120) LW(121) LW(122) LW(123) LW(124) LW(125) LW(126) LW(127)
    LW(128) LW(129) LW(130) LW(131) LW(132) LW(133) LW(134) LW(135)
    LW(136) LW(137) LW(138) LW(139) LW(140) LW(141) LW(142) LW(143)
    LW(144) LW(145) LW(146) LW(147) LW(148) LW(149)
    const float w150 = 0.f, w151 = 0.f;   // pad; fmacs with 0 fold away exactly

    // Pin: asm redefinition = not rematerializable, not sinkable.
#define PIN6(a,b,c,d,e,f) asm volatile("" : "+v"(w##a), "+v"(w##b), "+v"(w##c), "+v"(w##d), "+v"(w##e), "+v"(w##f));
    PIN6(0,1,2,3,4,5)        PIN6(6,7,8,9,10,11)       PIN6(12,13,14,15,16,17)
    PIN6(18,19,20,21,22,23)  PIN6(24,25,26,27,28,29)   PIN6(30,31,32,33,34,35)
    PIN6(36,37,38,39,40,41)  PIN6(42,43,44,45,46,47)   PIN6(48,49,50,51,52,53)
    PIN6(54,55,56,57,58,59)  PIN6(60,61,62,63,64,65)   PIN6(66,67,68,69,70,71)
    PIN6(72,73,74,75,76,77)  PIN6(78,79,80,81,82,83)   PIN6(84,85,86,87,88,89)
    PIN6(90,91,92,93,94,95)  PIN6(96,97,98,99,100,101) PIN6(102,103,104,105,106,107)
    PIN6(108,109,110,111,112,113) PIN6(114,115,116,117,118,119)
    PIN6(120,121,122,123,124,125) PIN6(126,127,128,129,130,131)
    PIN6(132,133,134,135,136,137) PIN6(138,139,140,141,142,143)
    PIN6(144,145,146,147,148,149)

    const float bhh = (tid < H3) ? b_hh[tid] : 0.f;

    float wih_r = 0.f, wih_z = 0.f, wih_n = 0.f;
    float bih_r = 0.f, bih_z = 0.f, bih_n = 0.f, wlin = 0.f;
    if (tid < HH) {
        wih_r = W_ih[tid];          bih_r = b_ih[tid];
        wih_z = W_ih[HH + tid];     bih_z = b_ih[HH + tid];
        wih_n = W_ih[2 * HH + tid]; bih_n = b_ih[2 * HH + tid];
        wlin  = W_lin[tid];
    }
    const float blin = b_lin[0];
    float hreg = 0.f;
    float* outb = out + (size_t)b * TT;

    __syncthreads();

    // ---- recurrence -----------------------------------------------------
    for (int t = 0; t < TT; ++t) {
        // phase 1: h . W_hh[row]. hv lane q holds h[4q..4q+3]; readlane
        // broadcasts to SGPR feeding v_fmac against resident weight regs.
        // Accumulation order IDENTICAL to the passing R1/R4 kernels.
        float4 hv = h4[lane];
        float a0 = 0.f, a1 = 0.f, a2 = 0.f, a3 = 0.f;
#define D4(Q, A, B, C, D) { \
        float hx = rl(hv.x, Q), hy = rl(hv.y, Q), hz = rl(hv.z, Q), hw = rl(hv.w, Q); \
        a0 = fmaf(hx, w##A, a0); \
        a1 = fmaf(hy, w##B, a1); \
        a2 = fmaf(hz, w##C, a2); \
        a3 = fmaf(hw, w##D, a3); }
        D4( 0,   0,   1,   2,   3) D4( 1,   4,   5,   6,   7)
        D4( 2,   8,   9,  10,  11) D4( 3,  12,  13,  14,  15)
        D4( 4,  16,  17,  18,  19) D4( 5,  20,  21,  22,  23)
        D4( 6,  24,  25,  26,  27) D4( 7,  28,  29,  30,  31)
        D4( 8,  32,  33,  34,  35) D4( 9,  36,  37,  38,  39)
        D4(10,  40,  41,  42,  43) D4(11,  44,  45,  46,  47)
        D4(12,  48,  49,  50,  51) D4(13,  52,  53,  54,  55)
        D4(14,  56,  57,  58,  59) D4(15,  60,  61,  62,  63)
        D4(16,  64,  65,  66,  67) D4(17,  68,  69,  70,  71)
        D4(18,  72,  73,  74,  75) D4(19,  76,  77,  78,  79)
        D4(20,  80,  81,  82,  83) D4(21,  84,  85,  86,  87)
        D4(22,  88,  89,  90,  91) D4(23,  92,  93,  94,  95)
        D4(24,  96,  97,  98,  99) D4(25, 100, 101, 102, 103)
        D4(26, 104, 105, 106, 107) D4(27, 108, 109, 110, 111)
        D4(28, 112, 113, 114, 115) D4(29, 116, 117, 118, 119)
        D4(30, 120, 121, 122, 123) D4(31, 124, 125, 126, 127)
        D4(32, 128, 129, 130, 131) D4(33, 132, 133, 134, 135)
        D4(34, 136, 137, 138, 139) D4(35, 140, 141, 142, 143)
        D4(36, 144, 145, 146, 147) D4(37, 148, 149, 150, 151)
        if (tid < H3) pre[tid] = (a0 + a1) + (a2 + a3) + bhh;
        __syncthreads();

        // phase 2: gates + hidden update (threads 0..149) -- identical to R4
        float yc = 0.f;
        if (tid < HH) {
            float x  = xrow[t];
            float gr = fmaf(x, wih_r, bih_r) + pre[tid];
            float gz = fmaf(x, wih_z, bih_z) + pre[HH + tid];
            float hn = pre[2 * HH + tid];
            float r  = 1.f / (1.f + __expf(-gr));
            float z  = 1.f / (1.f + __expf(-gz));
            float ta = fmaf(x, wih_n, bih_n) + r * hn;
            ta = fminf(fmaxf(ta, -15.f), 15.f);
            float e  = __expf(2.f * ta);
            float n  = (e - 1.f) / (e + 1.f);        // tanh
            float hnew = fmaf(z, hreg - n, n);       // (1-z)*n + z*h
            hnew = fmaxf(hnew, 0.f);                 // relu
            hreg = hnew;
            ((float*)h4)[tid] = hnew;
            yc = hnew * wlin;
        }
        if (tid < 192) {
            #pragma unroll
            for (int off = 32; off >= 1; off >>= 1)
                yc += __shfl_down(yc, off, 64);
            if (lane == 0) ypart[tid >> 6] = yc;
        }
        __syncthreads();
        if (tid == 0) outb[t] = ypart[0] + ypart[1] + ypart[2] + blin;
    }
}

extern "C" void kernel_launch(void* const* d_in, const int* in_sizes, int n_in,
                              void* d_out, int out_size, void* d_ws, size_t ws_size,
                              hipStream_t stream) {
    const float* input = (const float*)d_in[0];
    const float* W_ih  = (const float*)d_in[1];
    const float* W_hh  = (const float*)d_in[2];
    const float* b_ih  = (const float*)d_in[3];
    const float* b_hh  = (const float*)d_in[4];
    const float* W_lin = (const float*)d_in[5];
    const float* b_lin = (const float*)d_in[6];
    float* out = (float*)d_out;

    gru_seq_kernel<<<dim3(BB), dim3(512), 0, stream>>>(
        input, W_ih, W_hh, b_ih, b_hh, W_lin, b_lin, out);
}

// Round 6
// 3097.410 us; speedup vs baseline: 1.2835x; 1.2835x over previous
//
#include <hip/hip_runtime.h>
#include <math.h>

// B=256, T=2048, H=150. Sequential GRU, relu'd hidden, scalar linear head.
// 1 block / batch element (256 blocks = 256 CUs), 1024 threads.
//
// R6: the RA enforces a ~128-VGPR budget (default 4-waves/EU target) that no
// attribute/pin overrode in R1-R5 (VGPR_Count stuck at 88-92 = budget minus
// working set; spilled weights reloaded each step -> L2-bound 4640 cyc/step).
// Fix: 2-way split of each row's dot product BY ACCUMULATOR PAIR, preserving
// the passing kernel's summation order bit-exactly:
//     pre = ((a0+a1) + (a2+a3)) + bhh
// half 0 (even waves) computes chains a0,a1 (k = 0,1 mod 4; 76 weights),
// half 1 (odd waves)  computes chains a2,a3 (k = 2,3 mod 4; 76 weights),
// partials meet in LDS (preA/preB), phase 2 combines with the exact same
// association. Per-thread live set ~104 < 128 budget -> resident, no spill.
// h broadcast: one ds_read_b128/thread + 2 cndmask (wave-uniform half picks
// hv.x/y vs hv.z/w), then v_readlane -> SGPR feeding v_fmac (2 rl + 2 fmac
// per quad).

#define BB 256
#define TT 2048
#define HH 150
#define H3 450

__device__ __forceinline__ float rl(float v, int l) {
    return __uint_as_float(__builtin_amdgcn_readlane(__float_as_uint(v), l));
}

__global__ __launch_bounds__(1024)
__attribute__((amdgpu_waves_per_eu(4, 4)))
void gru_seq_kernel(
    const float* __restrict__ input,   // [B,T]
    const float* __restrict__ W_ih,    // [450,1]
    const float* __restrict__ W_hh,    // [450,150]
    const float* __restrict__ b_ih,    // [450]
    const float* __restrict__ b_hh,    // [450]
    const float* __restrict__ W_lin,   // [1,150]
    const float* __restrict__ b_lin,   // [1]
    float* __restrict__ out)           // [B,T]
{
    const int b    = blockIdx.x;
    const int tid  = threadIdx.x;
    const int lane = tid & 63;
    const int wid  = tid >> 6;         // 0..15
    const int half = wid & 1;          // wave-uniform accumulator-pair half
    const int row  = ((wid >> 1) << 6) + lane;   // 0..511
    const int act  = (row < H3);
    const int rowc = act ? row : (H3 - 1);

    __shared__ float  xrow[TT];        // 8 KB input row
    __shared__ float4 h4[64];          // h[0..149] zero-padded to 256 floats
    __shared__ float  preA[H3];        // a0+a1 partials
    __shared__ float  preB[H3];        // a2+a3 partials
    __shared__ float  ypart[4];

    // ---- prologue -------------------------------------------------------
    ((float2*)xrow)[tid] = ((const float2*)(input + (size_t)b * TT))[tid];
    if (tid < 64) h4[tid] = make_float4(0.f, 0.f, 0.f, 0.f);
    if (tid < 4)  ypart[tid] = 0.f;

    // This thread's 76 weights: wa_q = W[row][4q+2*half], wb_q = W[row][4q+1+2*half]
    const float* wr = W_hh + rowc * HH + 2 * half;
#define LW2(i) float wa##i = wr[4*(i)]; float wb##i = wr[4*(i)+1];
    LW2(0)  LW2(1)  LW2(2)  LW2(3)  LW2(4)  LW2(5)  LW2(6)  LW2(7)
    LW2(8)  LW2(9)  LW2(10) LW2(11) LW2(12) LW2(13) LW2(14) LW2(15)
    LW2(16) LW2(17) LW2(18) LW2(19) LW2(20) LW2(21) LW2(22) LW2(23)
    LW2(24) LW2(25) LW2(26) LW2(27) LW2(28) LW2(29) LW2(30) LW2(31)
    LW2(32) LW2(33) LW2(34) LW2(35) LW2(36)
    // q=37: half 0 -> k=148,149; half 1 -> k=150,151 (pad, must not load OOB)
    float wa37 = half ? 0.f : wr[148];
    float wb37 = half ? 0.f : wr[149];

    // Pin weights as asm redefinitions (not rematerializable / sinkable).
#define PINQ(i) asm volatile("" : "+v"(wa##i), "+v"(wb##i));
    PINQ(0)  PINQ(1)  PINQ(2)  PINQ(3)  PINQ(4)  PINQ(5)  PINQ(6)  PINQ(7)
    PINQ(8)  PINQ(9)  PINQ(10) PINQ(11) PINQ(12) PINQ(13) PINQ(14) PINQ(15)
    PINQ(16) PINQ(17) PINQ(18) PINQ(19) PINQ(20) PINQ(21) PINQ(22) PINQ(23)
    PINQ(24) PINQ(25) PINQ(26) PINQ(27) PINQ(28) PINQ(29) PINQ(30) PINQ(31)
    PINQ(32) PINQ(33) PINQ(34) PINQ(35) PINQ(36) PINQ(37)

    // Phase-2 constants (threads 0..149)
    float wih_r = 0.f, wih_z = 0.f, wih_n = 0.f;
    float bih_r = 0.f, bih_z = 0.f, bih_n = 0.f, wlin = 0.f;
    float bhh_r = 0.f, bhh_z = 0.f, bhh_n = 0.f;
    if (tid < HH) {
        wih_r = W_ih[tid];          bih_r = b_ih[tid];          bhh_r = b_hh[tid];
        wih_z = W_ih[HH + tid];     bih_z = b_ih[HH + tid];     bhh_z = b_hh[HH + tid];
        wih_n = W_ih[2 * HH + tid]; bih_n = b_ih[2 * HH + tid]; bhh_n = b_hh[2 * HH + tid];
        wlin  = W_lin[tid];
    }
    const float blin = b_lin[0];
    float hreg = 0.f;
    float* outb  = out + (size_t)b * TT;
    float* preH  = half ? preB : preA;

    __syncthreads();

    // ---- recurrence -----------------------------------------------------
    for (int t = 0; t < TT; ++t) {
        // phase 1: two of the four stride-4 fma chains for this row.
        // hv lane q holds h[4q..4q+3]; wave-uniform half selects components
        // BEFORE readlane, so rl(hA,q) broadcasts h[4q+2*half].
        float4 hv = h4[lane];
        float hA = half ? hv.z : hv.x;
        float hB = half ? hv.w : hv.y;
        float a0 = 0.f, a1 = 0.f;
#define DQ(q) { float s0 = rl(hA, q); float s1 = rl(hB, q); \
                a0 = fmaf(s0, wa##q, a0); a1 = fmaf(s1, wb##q, a1); }
        DQ(0)  DQ(1)  DQ(2)  DQ(3)  DQ(4)  DQ(5)  DQ(6)  DQ(7)
        DQ(8)  DQ(9)  DQ(10) DQ(11) DQ(12) DQ(13) DQ(14) DQ(15)
        DQ(16) DQ(17) DQ(18) DQ(19) DQ(20) DQ(21) DQ(22) DQ(23)
        DQ(24) DQ(25) DQ(26) DQ(27) DQ(28) DQ(29) DQ(30) DQ(31)
        DQ(32) DQ(33) DQ(34) DQ(35) DQ(36) DQ(37)
        if (act) preH[row] = a0 + a1;       // half0: a0+a1, half1: a2+a3
        __syncthreads();

        // phase 2: gates + hidden update (threads 0..149).
        // pre = ((a0+a1) + (a2+a3)) + bhh -- exact R1/R4 association.
        float yc = 0.f;
        if (tid < HH) {
            float x  = xrow[t];
            float pr = (preA[tid]          + preB[tid])          + bhh_r;
            float pz = (preA[HH + tid]     + preB[HH + tid])     + bhh_z;
            float pn = (preA[2 * HH + tid] + preB[2 * HH + tid]) + bhh_n;
            float gr = fmaf(x, wih_r, bih_r) + pr;
            float gz = fmaf(x, wih_z, bih_z) + pz;
            float r  = 1.f / (1.f + __expf(-gr));
            float z  = 1.f / (1.f + __expf(-gz));
            float ta = fmaf(x, wih_n, bih_n) + r * pn;
            ta = fminf(fmaxf(ta, -15.f), 15.f);
            float e  = __expf(2.f * ta);
            float n  = (e - 1.f) / (e + 1.f);        // tanh
            float hnew = fmaf(z, hreg - n, n);       // (1-z)*n + z*h
            hnew = fmaxf(hnew, 0.f);                 // relu
            hreg = hnew;
            ((float*)h4)[tid] = hnew;
            yc = hnew * wlin;
        }
        if (tid < 192) {
            #pragma unroll
            for (int off = 32; off >= 1; off >>= 1)
                yc += __shfl_down(yc, off, 64);
            if (lane == 0) ypart[wid] = yc;
        }
        __syncthreads();
        if (tid == 0) outb[t] = ypart[0] + ypart[1] + ypart[2] + blin;
    }
}

extern "C" void kernel_launch(void* const* d_in, const int* in_sizes, int n_in,
                              void* d_out, int out_size, void* d_ws, size_t ws_size,
                              hipStream_t stream) {
    const float* input = (const float*)d_in[0];
    const float* W_ih  = (const float*)d_in[1];
    const float* W_hh  = (const float*)d_in[2];
    const float* b_ih  = (const float*)d_in[3];
    const float* b_hh  = (const float*)d_in[4];
    const float* W_lin = (const float*)d_in[5];
    const float* b_lin = (const float*)d_in[6];
    float* out = (float*)d_out;

    gru_seq_kernel<<<dim3(BB), dim3(1024), 0, stream>>>(
        input, W_ih, W_hh, b_ih, b_hh, W_lin, b_lin, out);
}